// Round 11
// baseline (223.463 us; speedup 1.0000x reference)
//
#include <hip/hip_runtime.h>
#include <stdint.h>

#define NB 32768
#define NPASS 4
#define FULL27 0x07FFFFFFu
#define PPW 16                    // 16 puzzles per single-wave block (4 lanes each)
#define NBLK (NB / PPW)           // 2048 blocks x 64 threads = 2048 waves, 8 blk/CU
#define POOL_DW 368               // 16*729 = 11664 bits = 364.5 dw (+pad)
#define BLK_V4 2916               // 16*729/4 float4s per block (exact)

// Per-band bitboard: digit d, band b (rows 3b..3b+2), bit (r*9+c).
// BOX k mask within band: 0x1C0E07 << 3k ; COL c: 0x40201 << c ; ROW r: 0x1FF << 9r
// Flat float layout: puzzle p, digit d, band b, cell j == p*729 + d*81 + b*27 + j.
// Pool layout: bit j of block pool == float blk*11664 + j.
//
// SESSION LEDGER:
//   r15 (216.5us): 3 lanes/puzzle, ds_bpermute. kernel 107us.
//   r16 (213.5us): quad DPP bands, 2048x64 blocks, ballot pack (~40us).
//   r17 (241.6us REGRESSION): solve at 512 waves -> half the SIMDs empty.
//   r18/r20 (216.2us): split kernels. Solve 72us @ VALUBusy 73-75%.
//   r21 (215.6us): fused coalesced DPP pack, 512x256. VGPR=48, 1 outstanding
//     load/wave -> pack ~31us stall.
//   r22 (209.7us): +launch_bounds+src ping-pong: compiler collapses reg dbuf.
//   r23 (207.2us): +sched_barrier fences: profiled 142 (SB defeats scheduler).
//   r24 (213.4us): global_load_lds 3-buf ring: profiled 149. KEY INSIGHT:
//     bench-implied kernel ~97-105us for ALL of r21-r24 (rocprof inflates the
//     speculative variants); pack is ~3TB/s no matter the pipelining mechanism.
//     Phases run in LOCKSTEP at 2 big blocks/CU: memory phases never overlap
//     the VALU phase across blocks.
//   r25/r26 (this, resubmit after infra timeout): 2048 single-wave blocks
//     (16 puzzles/wave) -> 8 blocks/CU with async retirement = cross-block
//     phase stagger (pack VMEM overlaps solve VALU). Barriers ~free
//     (single-wave). Plus broadcast-mul strength reduction (v_mul_lo_u32 is
//     quarter-rate; all ops carry-free or/shift). Predict kernel ~90, bench ~200.

__device__ __forceinline__ uint32_t colfold(uint32_t w) {
    return (w | (w >> 9) | (w >> 18)) & 0x1FFu;
}
__device__ __forceinline__ uint32_t colmaj2(uint32_t w) {   // columns with >=2 bits in band
    return ((w & (w >> 9)) | ((w | (w >> 9)) & (w >> 18))) & 0x1FFu;
}
// broadcast multiplies, strength-reduced (operands carry-free by construction):
__device__ __forceinline__ uint32_t bcast3(uint32_t x) {    // x*0x40201, x<=0x1FF
    return x | (x << 9) | (x << 18);
}
__device__ __forceinline__ uint32_t mul7s(uint32_t x) {     // x*7, bits spaced >=3
    return x | (x << 1) | (x << 2);
}
// quad_perm rotations within the 4-lane quad: band b reads band (b+1)%3 / (b-1)%3.
// ctrl = sel0 | sel1<<2 | sel2<<4 | sel3<<6 : [1,2,0,0]=0x09 ; [2,0,1,0]=0x12
__device__ __forceinline__ uint32_t rotA(uint32_t v) {      // from band+1 (mod 3)
    return (uint32_t)__builtin_amdgcn_update_dpp(0, (int)v, 0x09, 0xF, 0xF, true);
}
__device__ __forceinline__ uint32_t rotB(uint32_t v) {      // from band-1 (mod 3)
    return (uint32_t)__builtin_amdgcn_update_dpp(0, (int)v, 0x12, 0xF, 0xF, true);
}
// pack-tree swaps: quad_perm [1,0,3,2]=0xB1 (lane^1), [2,3,0,1]=0x4E (lane^2)
__device__ __forceinline__ uint32_t dppx1(uint32_t v) {
    return (uint32_t)__builtin_amdgcn_update_dpp(0, (int)v, 0xB1, 0xF, 0xF, true);
}
__device__ __forceinline__ uint32_t dppx2(uint32_t v) {
    return (uint32_t)__builtin_amdgcn_update_dpp(0, (int)v, 0x4E, 0xF, 0xF, true);
}

__global__ __launch_bounds__(64)
void sudoku_kernel(const uint32_t* __restrict__ in, float* __restrict__ out,
                   float* __restrict__ solved) {
    __shared__ uint32_t pool[POOL_DW];      // wave-private bit pool
    const int lane = threadIdx.x;
    const int q = lane >> 2;                // puzzle slot 0..15
    const int band = lane & 3;              // 0..2 live, 3 idle in solve
    const int P0 = blockIdx.x * PPW;

    // ---------------- PACK: coalesced vec4 -> DPP nibble tree -> pool ----------
    // iter i: lane loads float4 #(i*64+lane) (wave = 1KB contiguous).
    // nibble n from exp bit 23; xor1 DPP -> byte (even lanes); xor2 -> u16
    // (lane%4==0); u16 store at t=(i*64+lane)>>2. r21-r24 proved ~3TB/s is the
    // per-wave ceiling here; stagger across 8 blocks/CU hides the rest.
    {
        const uint4* src4 = (const uint4*)in + (size_t)blockIdx.x * BLK_V4;
        uint16_t* hp = (uint16_t*)pool;
        #pragma unroll 1
        for (int i = 0; i < 46; ++i) {              // 46*64 = 2944 >= 2916
            int g = i * 64 + lane;
            int gc = g > BLK_V4 - 1 ? BLK_V4 - 1 : g;
            uint4 v = src4[gc];
            // inputs are exactly 0.0f/1.0f -> bit 23 of the pattern is the flag
            uint32_t n = ((v.x >> 23) & 1u) | ((v.y >> 22) & 2u)
                       | ((v.z >> 21) & 4u) | ((v.w >> 20) & 8u);
            uint32_t b = n | (dppx1(n) << 4);       // byte, valid on even lanes
            uint32_t h = b | (dppx2(b) << 8);       // u16, valid on lane%4==0
            if ((lane & 3) == 0) {
                int t = g >> 2;                     // unclamped index
                if (t < 730) hp[t] = (uint16_t)h;   // t=729 garbage, unread
            }
        }
    }
    __syncthreads();                                // single-wave: ~free

    // ---- extract 9 band-words for this lane (band 3 reads in-bounds garbage)
    uint32_t bd[9];
    {
        const int bb0 = q * 729 + band * 27;
        #pragma unroll
        for (int d = 0; d < 9; ++d) {
            int bit = bb0 + d * 81;
            int di = bit >> 5, sh = bit & 31;
            uint64_t both = (uint64_t)pool[di] | ((uint64_t)pool[di + 1] << 32);
            bd[d] = (uint32_t)(both >> sh) & FULL27;
        }
    }
    __syncthreads();

    // ---------------- SOLVE (r16/r20-validated quad-DPP logic; muls reduced) ---
    #pragma unroll 1
    for (int pass = 0; pass < NPASS; ++pass) {
        // ---------- filter 'box' (band-local) ----------
        {
            uint32_t on = 0, tw = 0, fo = 0;
            #pragma unroll
            for (int d = 0; d < 9; ++d) {
                uint32_t c = on & bd[d];
                on ^= bd[d]; fo |= tw & c; tw ^= c;
            }
            uint32_t ex1 = on & ~tw & ~fo;
            #pragma unroll
            for (int d = 0; d < 9; ++d) {
                uint32_t s = bd[d] & ex1;
                #pragma unroll
                for (int k = 0; k < 3; ++k) {
                    uint32_t bm = 0x1C0E07u << (3 * k);
                    uint32_t sm = s & bm;
                    uint32_t multi = sm & (sm - 1u);
                    uint32_t keep = (sm == 0u) ? 0xFFFFFFFFu : (~bm | (multi ? 0u : sm));
                    bd[d] &= keep;
                }
            }
        }

        // ---------- pointing 'h' (band-local) ----------
        #pragma unroll
        for (int d = 0; d < 9; ++d) {
            uint32_t w = bd[d];
            uint32_t t = (w | (w >> 1) | (w >> 2)) & 0x01249249u;
            uint32_t sum = (t & 0x1FFu) + ((t >> 9) & 0x1FFu) + ((t >> 18) & 0x1FFu);
            uint32_t single = sum & ~(sum >> 1) & 0x49u;
            uint32_t point = t & bcast3(single);    // single in {0,3,6}: carry-free
            uint32_t clearm = 0;
            #pragma unroll
            for (int r = 0; r < 3; ++r) {
                uint32_t pr = (point >> (9 * r)) & 0x1FFu;
                uint32_t multi = pr & (pr - 1u);
                uint32_t segkeep = multi ? 0u : mul7s(pr);  // pr single-bit here
                uint32_t rc = pr ? ((0x1FFu & ~segkeep) << (9 * r)) : 0u;
                clearm |= rc;
            }
            bd[d] = w & ~clearm;
        }

        // ---------- pointing 'v' (cross-band via DPP) ----------
        {
            uint32_t pnt[9];
            #pragma unroll
            for (int d = 0; d < 9; ++d) {
                uint32_t w = bd[d];
                uint32_t qq = colfold(w);
                uint32_t u = (qq & 0x49u) + ((qq >> 1) & 0x49u) + ((qq >> 2) & 0x49u);
                uint32_t single = u & ~(u >> 1) & 0x49u;
                pnt[d] = qq & mul7s(single);        // single bits spaced 3: carry-free
            }
            #pragma unroll
            for (int d = 0; d < 9; ++d) {
                uint32_t o = rotA(pnt[d]) | rotB(pnt[d]);
                bd[d] &= ~bcast3(o);
            }
        }

        // ---------- unique 'h' (band-local) ----------
        {
            uint32_t hid[9], has = 0;
            #pragma unroll
            for (int d = 0; d < 9; ++d) {
                uint32_t w = bd[d], h = 0;
                #pragma unroll
                for (int r = 0; r < 3; ++r) {
                    uint32_t x = w & (0x1FFu << (9 * r));
                    h |= (x & (x - 1u)) ? 0u : x;
                }
                hid[d] = h; has |= h;
            }
            #pragma unroll
            for (int d = 0; d < 9; ++d) bd[d] = (bd[d] & ~has) | hid[d];
        }

        // ---------- unique 'v' (cross-band via DPP) ----------
        {
            uint32_t hid[9], has = 0;
            #pragma unroll
            for (int d = 0; d < 9; ++d) {
                uint32_t w = bd[d];
                uint32_t q0 = colfold(w), m0 = colmaj2(w);
                uint32_t ex = q0 | (m0 << 9);
                uint32_t ea = rotA(ex);
                uint32_t eb = rotB(ex);
                uint32_t qa = ea & 0x1FFu, ma = ea >> 9;
                uint32_t qb = eb & 0x1FFu, mb = eb >> 9;
                uint32_t ge2 = m0 | ma | mb | (q0 & qa) | (q0 & qb) | (qa & qb);
                uint32_t ex1c = (q0 | qa | qb) & ~ge2;   // column total count == 1
                hid[d] = w & bcast3(ex1c & q0);
                has |= hid[d];
            }
            #pragma unroll
            for (int d = 0; d < 9; ++d) bd[d] = (bd[d] & ~has) | hid[d];
        }

        // ---------- unique 'box' (band-local) ----------
        {
            uint32_t hid[9], has = 0;
            #pragma unroll
            for (int d = 0; d < 9; ++d) {
                uint32_t w = bd[d], h = 0;
                #pragma unroll
                for (int k = 0; k < 3; ++k) {
                    uint32_t x = w & (0x1C0E07u << (3 * k));
                    h |= (x & (x - 1u)) ? 0u : x;
                }
                hid[d] = h; has |= h;
            }
            #pragma unroll
            for (int d = 0; d < 9; ++d) bd[d] = (bd[d] & ~has) | hid[d];
        }

        // ---------- doubles 'v' twice (cross-band via DPP) ----------
        #pragma unroll 1
        for (int rep = 0; rep < 2; ++rep) {
            uint32_t on = 0, tw = 0, fo = 0;
            #pragma unroll
            for (int d = 0; d < 9; ++d) {
                uint32_t c = on & bd[d];
                on ^= bd[d]; fo |= tw & c; tw ^= c;
            }
            uint32_t ex2 = tw & ~on & ~fo;
            uint32_t Q[9], K[9];
            #pragma unroll
            for (int d = 0; d < 9; ++d) { Q[d] = bd[d] & ex2; K[d] = 0u; }
            #pragma unroll
            for (int d1 = 0; d1 < 9; ++d1)
                #pragma unroll
                for (int d2 = d1 + 1; d2 < 9; ++d2) {
                    uint32_t P = Q[d1] & Q[d2];
                    uint32_t f0 = colfold(P), g0 = colmaj2(P);
                    uint32_t ex = f0 | (g0 << 9);
                    uint32_t ea = rotA(ex);
                    uint32_t eb = rotB(ex);
                    uint32_t fa = ea & 0x1FFu, ga = ea >> 9;
                    uint32_t fb = eb & 0x1FFu, gb = eb >> 9;
                    // columns with >=2 exact-pair cells across the full column
                    uint32_t dup = g0 | ga | gb | (f0 & fa) | (f0 & fb) | (fa & fb);
                    uint32_t sK = P & bcast3(dup);
                    K[d1] |= sK; K[d2] |= sK;
                }
            #pragma unroll
            for (int d = 0; d < 9; ++d) {
                uint32_t kc = colfold(K[d]);
                uint32_t cols = kc | rotA(kc) | rotB(kc);
                uint32_t em = bcast3(cols);
                bd[d] = (bd[d] & ~em) | K[d];
            }
        }

        // ---------- doubles 'box' (band-local) ----------
        {
            uint32_t on = 0, tw = 0, fo = 0;
            #pragma unroll
            for (int d = 0; d < 9; ++d) {
                uint32_t c = on & bd[d];
                on ^= bd[d]; fo |= tw & c; tw ^= c;
            }
            uint32_t ex2 = tw & ~on & ~fo;
            uint32_t Q[9], K[9];
            #pragma unroll
            for (int d = 0; d < 9; ++d) { Q[d] = bd[d] & ex2; K[d] = 0u; }
            #pragma unroll
            for (int d1 = 0; d1 < 9; ++d1)
                #pragma unroll
                for (int d2 = d1 + 1; d2 < 9; ++d2) {
                    uint32_t P = Q[d1] & Q[d2];
                    #pragma unroll
                    for (int k = 0; k < 3; ++k) {
                        uint32_t m = P & (0x1C0E07u << (3 * k));
                        uint32_t s = (m & (m - 1u)) ? m : 0u;
                        K[d1] |= s; K[d2] |= s;
                    }
                }
            #pragma unroll
            for (int d = 0; d < 9; ++d)
                #pragma unroll
                for (int k = 0; k < 3; ++k) {
                    uint32_t bm = 0x1C0E07u << (3 * k);
                    uint32_t t = K[d] & bm;
                    uint32_t mask = t ? (~bm | t) : 0xFFFFFFFFu;
                    bd[d] &= mask;
                }
        }
    } // passes

    // ---------------- solved flag (AND across quad via DPP) ----------------
    {
        uint32_t on = 0, tw = 0, fo = 0;
        #pragma unroll
        for (int d = 0; d < 9; ++d) {
            uint32_t c = on & bd[d];
            on ^= bd[d]; fo |= tw & c; tw ^= c;
        }
        uint32_t okb = ((on & ~tw & ~fo) == FULL27) ? 1u : 0u;
        uint32_t all = okb & rotA(okb) & rotB(okb);
        if (band == 0) solved[P0 + q] = all ? 1.0f : 0.0f;
    }

    // ---------------- EXPAND: repack to pool bitstream -> float4 stores --------
    #pragma unroll
    for (int i = 0; i < 6; ++i) {
        int j = i * 64 + lane;
        if (j < POOL_DW) pool[j] = 0u;
    }
    __syncthreads();
    if (band != 3) {
        const int pbit = q * 729;
        #pragma unroll
        for (int d = 0; d < 9; ++d) {
            int bitbase = pbit + d * 81 + band * 27;
            int di = bitbase >> 5;
            int sh = bitbase & 31;
            uint64_t both = (uint64_t)bd[d] << sh;
            atomicOr(&pool[di], (uint32_t)both);
            atomicOr(&pool[di + 1], (uint32_t)(both >> 32));
        }
    }
    __syncthreads();
    {
        float4* dst4 = (float4*)(out + (size_t)P0 * 729);  // 11664*blk floats: aligned
        #pragma unroll 4
        for (int i = 0; i < 46; ++i) {                     // 2916 float4s / 64 lanes
            int j = i * 64 + lane;
            if (j < BLK_V4) {
                uint32_t nib = (pool[j >> 3] >> ((j & 7) * 4)) & 0xFu;
                dst4[j] = make_float4((float)(nib & 1u), (float)((nib >> 1) & 1u),
                                      (float)((nib >> 2) & 1u), (float)((nib >> 3) & 1u));
            }
        }
    }
}

extern "C" void kernel_launch(void* const* d_in, const int* in_sizes, int n_in,
                              void* d_out, int out_size, void* d_ws, size_t ws_size,
                              hipStream_t stream) {
    const uint32_t* in = (const uint32_t*)d_in[0];   // float32 bits; 0.0f / 1.0f
    float* out = (float*)d_out;
    float* solved = out + (size_t)NB * 729;
    // 2048 single-wave blocks (16 puzzles each) -> 8 blocks/CU, phase stagger
    sudoku_kernel<<<NBLK, 64, 0, stream>>>(in, out, solved);
}

// Round 12
// 220.990 us; speedup vs baseline: 1.0112x; 1.0112x over previous
//
#include <hip/hip_runtime.h>
#include <stdint.h>

#define NB 32768
#define NPASS 4
#define FULL27 0x07FFFFFFu
#define PUZ_PER_BLK 64            // 64 puzzles/block (16 per wave, 4 lanes each)
#define SOLVE_BLKS (NB / PUZ_PER_BLK)   // 512 blocks x 256 threads = 2048 waves
#define BLK_DW 1458               // 64*729/32 dwords of bits per block (exact)
#define BLK_V4 11664              // 64*729/4 float4s per block (exact)

// Per-band bitboard: digit d, band b (rows 3b..3b+2), bit (r*9+c).
// BOX k mask within band: 0x1C0E07 << 3k ; COL c: 0x40201 << c ; ROW r: 0x1FF << 9r
// Flat float layout: puzzle p, digit d, band b, cell j == p*729 + d*81 + b*27 + j.
// Pool layout: bit j of block pool == float blk*46656 + j.
//
// SESSION LEDGER:
//   r15 (216.5us): 3 lanes/puzzle, ds_bpermute. kernel 107us.
//   r16 (213.5us): quad DPP bands. LDS_CONF 3.0M->192K, VALUBusy 42->55.
//   r17 (241.6us REGRESSION): solve at 512 waves -> half the SIMDs empty.
//   r18/r20 (216.2us): split kernels. Solve 72us @ VALUBusy 73-75%.
//   r21 (215.6us): fused coalesced DPP pack, 512x256. kernel 104.2.
//   r22 (209.7us, BEST): +launch_bounds(256,2). kernel 101.6. Pack ~31us =
//     L3/HBM mixed read BW (~3.2TB/s, FETCH=47MB: input half L3-resident) —
//     NOT latency; solve ~50 VALU-bound; expand ~18 near write floor.
//   r23 (207.2): sched_barrier fences -> profiled 142 (defeats scheduler).
//   r24 (213.4): global_load_lds ring -> no gain (pack is BW- not latency-bound).
//   r25/r26 (223.5 REGRESSION): single-wave blocks + manual or/shift broadcast
//     "strength reduction". WRONG: x*0x40201 (x<=0x1FF) compiles to full-rate
//     v_mul_u32_u24 (1 inst); manual form = 4 inst in the hottest loops. Also
//     single-wave stagger = no benefit (chip-wide phase lockstep persists).
//   r27 (this): r22 EXACTLY + per-wave fixpoint early-exit on the pass loop.
//     bd unchanged by a pass => later passes provably no-op (deterministic).
//     ballot excludes band-3 garbage lanes. ~25 inst/pass check vs ~2200/pass.
//     Predict: converged-by-3 data -> kernel ~90, bench ~199; else neutral
//     (then phase floors = structural ceiling).

__device__ __forceinline__ uint32_t colfold(uint32_t w) {
    return (w | (w >> 9) | (w >> 18)) & 0x1FFu;
}
__device__ __forceinline__ uint32_t colmaj2(uint32_t w) {   // columns with >=2 bits in band
    return ((w & (w >> 9)) | ((w | (w >> 9)) & (w >> 18))) & 0x1FFu;
}
// quad_perm rotations within the 4-lane quad: band b reads band (b+1)%3 / (b-1)%3.
// ctrl = sel0 | sel1<<2 | sel2<<4 | sel3<<6 : [1,2,0,0]=0x09 ; [2,0,1,0]=0x12
__device__ __forceinline__ uint32_t rotA(uint32_t v) {      // from band+1 (mod 3)
    return (uint32_t)__builtin_amdgcn_update_dpp(0, (int)v, 0x09, 0xF, 0xF, true);
}
__device__ __forceinline__ uint32_t rotB(uint32_t v) {      // from band-1 (mod 3)
    return (uint32_t)__builtin_amdgcn_update_dpp(0, (int)v, 0x12, 0xF, 0xF, true);
}
// pack-tree swaps: quad_perm [1,0,3,2]=0xB1 (lane^1), [2,3,0,1]=0x4E (lane^2)
__device__ __forceinline__ uint32_t dppx1(uint32_t v) {
    return (uint32_t)__builtin_amdgcn_update_dpp(0, (int)v, 0xB1, 0xF, 0xF, true);
}
__device__ __forceinline__ uint32_t dppx2(uint32_t v) {
    return (uint32_t)__builtin_amdgcn_update_dpp(0, (int)v, 0x4E, 0xF, 0xF, true);
}

__global__ __launch_bounds__(256, 2)
void sudoku_kernel(const uint32_t* __restrict__ in, float* __restrict__ out,
                   float* __restrict__ solved) {
    __shared__ uint32_t pool[BLK_DW + 2];   // 46656 bits (+pad for extract's 64b read)
    const int tid = threadIdx.x;
    const int q = tid >> 2;                 // puzzle slot 0..63
    const int band = tid & 3;               // 0..2 live, 3 idle in solve
    const int P0 = blockIdx.x * PUZ_PER_BLK;

    // ---------------- PACK (fused, coalesced DPP tree; r22-validated) ----------
    // iter i: thread loads float4 #(i*256+tid) (contiguous). Nibble from exp
    // bit 23; DPP xor1 -> byte (even lanes); xor2 -> u16 (lane%4==0); u16 store.
    {
        const uint4* src4 = (const uint4*)in + (size_t)blockIdx.x * BLK_V4;
        uint16_t* hp = (uint16_t*)pool;
        #pragma unroll 1
        for (int i = 0; i < 46; ++i) {              // 46*256 = 11776 >= 11664
            int g = i * 256 + tid;
            int gc = g > BLK_V4 - 1 ? BLK_V4 - 1 : g;
            uint4 v = src4[gc];
            // inputs are exactly 0.0f/1.0f -> bit 23 of the pattern is the flag
            uint32_t n = ((v.x >> 23) & 1u) | ((v.y >> 22) & 2u)
                       | ((v.z >> 21) & 4u) | ((v.w >> 20) & 8u);
            uint32_t b = n | (dppx1(n) << 4);       // byte, valid on even lanes
            uint32_t h = b | (dppx2(b) << 8);       // u16, valid on lane%4==0
            if ((tid & 3) == 0) {
                int t = g >> 2;                     // unclamped
                if (t < 2 * BLK_DW) hp[t] = (uint16_t)h;
            }
        }
    }
    __syncthreads();

    // ---- extract 9 band-words for this lane (band 3 reads in-bounds garbage)
    uint32_t bd[9];
    {
        const int bb0 = q * 729 + band * 27;
        #pragma unroll
        for (int d = 0; d < 9; ++d) {
            int bit = bb0 + d * 81;
            int di = bit >> 5, sh = bit & 31;
            uint64_t both = (uint64_t)pool[di] | ((uint64_t)pool[di + 1] << 32);
            bd[d] = (uint32_t)(both >> sh) & FULL27;
        }
    }
    __syncthreads();    // extraction done before pool reuse for expand

    // ---------------- SOLVE (r16/r20-validated quad-DPP logic) -----------------
    // Fixpoint early-exit: if a full pass leaves every live lane's bd unchanged,
    // later passes are identical no-ops (pure function of bd) -> wave breaks.
    // No barriers inside the loop; waves reconverge at the expand barrier.
    #pragma unroll 1
    for (int pass = 0; pass < NPASS; ++pass) {
        uint32_t old0 = bd[0], old1 = bd[1], old2 = bd[2], old3 = bd[3],
                 old4 = bd[4], old5 = bd[5], old6 = bd[6], old7 = bd[7],
                 old8 = bd[8];

        // ---------- filter 'box' (band-local) ----------
        {
            uint32_t on = 0, tw = 0, fo = 0;
            #pragma unroll
            for (int d = 0; d < 9; ++d) {
                uint32_t c = on & bd[d];
                on ^= bd[d]; fo |= tw & c; tw ^= c;
            }
            uint32_t ex1 = on & ~tw & ~fo;
            #pragma unroll
            for (int d = 0; d < 9; ++d) {
                uint32_t s = bd[d] & ex1;
                #pragma unroll
                for (int k = 0; k < 3; ++k) {
                    uint32_t bm = 0x1C0E07u << (3 * k);
                    uint32_t sm = s & bm;
                    uint32_t multi = sm & (sm - 1u);
                    uint32_t keep = (sm == 0u) ? 0xFFFFFFFFu : (~bm | (multi ? 0u : sm));
                    bd[d] &= keep;
                }
            }
        }

        // ---------- pointing 'h' (band-local) ----------
        #pragma unroll
        for (int d = 0; d < 9; ++d) {
            uint32_t w = bd[d];
            uint32_t t = (w | (w >> 1) | (w >> 2)) & 0x01249249u;
            uint32_t sum = (t & 0x1FFu) + ((t >> 9) & 0x1FFu) + ((t >> 18) & 0x1FFu);
            uint32_t single = sum & ~(sum >> 1) & 0x49u;
            uint32_t point = t & (single * 0x40201u);
            uint32_t clearm = 0;
            #pragma unroll
            for (int r = 0; r < 3; ++r) {
                uint32_t pr = (point >> (9 * r)) & 0x1FFu;
                uint32_t multi = pr & (pr - 1u);
                uint32_t segkeep = multi ? 0u : pr * 7u;
                uint32_t rc = pr ? ((0x1FFu & ~segkeep) << (9 * r)) : 0u;
                clearm |= rc;
            }
            bd[d] = w & ~clearm;
        }

        // ---------- pointing 'v' (cross-band via DPP) ----------
        {
            uint32_t pnt[9];
            #pragma unroll
            for (int d = 0; d < 9; ++d) {
                uint32_t w = bd[d];
                uint32_t qq = colfold(w);
                uint32_t u = (qq & 0x49u) + ((qq >> 1) & 0x49u) + ((qq >> 2) & 0x49u);
                uint32_t single = u & ~(u >> 1) & 0x49u;
                pnt[d] = qq & (single * 7u);
            }
            #pragma unroll
            for (int d = 0; d < 9; ++d) {
                uint32_t o = rotA(pnt[d]) | rotB(pnt[d]);
                bd[d] &= ~(o * 0x40201u);
            }
        }

        // ---------- unique 'h' (band-local) ----------
        {
            uint32_t hid[9], has = 0;
            #pragma unroll
            for (int d = 0; d < 9; ++d) {
                uint32_t w = bd[d], h = 0;
                #pragma unroll
                for (int r = 0; r < 3; ++r) {
                    uint32_t x = w & (0x1FFu << (9 * r));
                    h |= (x & (x - 1u)) ? 0u : x;
                }
                hid[d] = h; has |= h;
            }
            #pragma unroll
            for (int d = 0; d < 9; ++d) bd[d] = (bd[d] & ~has) | hid[d];
        }

        // ---------- unique 'v' (cross-band via DPP) ----------
        {
            uint32_t hid[9], has = 0;
            #pragma unroll
            for (int d = 0; d < 9; ++d) {
                uint32_t w = bd[d];
                uint32_t q0 = colfold(w), m0 = colmaj2(w);
                uint32_t ex = q0 | (m0 << 9);
                uint32_t ea = rotA(ex);
                uint32_t eb = rotB(ex);
                uint32_t qa = ea & 0x1FFu, ma = ea >> 9;
                uint32_t qb = eb & 0x1FFu, mb = eb >> 9;
                uint32_t ge2 = m0 | ma | mb | (q0 & qa) | (q0 & qb) | (qa & qb);
                uint32_t ex1c = (q0 | qa | qb) & ~ge2;   // column total count == 1
                hid[d] = w & ((ex1c & q0) * 0x40201u);
                has |= hid[d];
            }
            #pragma unroll
            for (int d = 0; d < 9; ++d) bd[d] = (bd[d] & ~has) | hid[d];
        }

        // ---------- unique 'box' (band-local) ----------
        {
            uint32_t hid[9], has = 0;
            #pragma unroll
            for (int d = 0; d < 9; ++d) {
                uint32_t w = bd[d], h = 0;
                #pragma unroll
                for (int k = 0; k < 3; ++k) {
                    uint32_t x = w & (0x1C0E07u << (3 * k));
                    h |= (x & (x - 1u)) ? 0u : x;
                }
                hid[d] = h; has |= h;
            }
            #pragma unroll
            for (int d = 0; d < 9; ++d) bd[d] = (bd[d] & ~has) | hid[d];
        }

        // ---------- doubles 'v' twice (cross-band via DPP) ----------
        #pragma unroll 1
        for (int rep = 0; rep < 2; ++rep) {
            uint32_t on = 0, tw = 0, fo = 0;
            #pragma unroll
            for (int d = 0; d < 9; ++d) {
                uint32_t c = on & bd[d];
                on ^= bd[d]; fo |= tw & c; tw ^= c;
            }
            uint32_t ex2 = tw & ~on & ~fo;
            uint32_t Q[9], K[9];
            #pragma unroll
            for (int d = 0; d < 9; ++d) { Q[d] = bd[d] & ex2; K[d] = 0u; }
            #pragma unroll
            for (int d1 = 0; d1 < 9; ++d1)
                #pragma unroll
                for (int d2 = d1 + 1; d2 < 9; ++d2) {
                    uint32_t P = Q[d1] & Q[d2];
                    uint32_t f0 = colfold(P), g0 = colmaj2(P);
                    uint32_t ex = f0 | (g0 << 9);
                    uint32_t ea = rotA(ex);
                    uint32_t eb = rotB(ex);
                    uint32_t fa = ea & 0x1FFu, ga = ea >> 9;
                    uint32_t fb = eb & 0x1FFu, gb = eb >> 9;
                    // columns with >=2 exact-pair cells across the full column
                    uint32_t dup = g0 | ga | gb | (f0 & fa) | (f0 & fb) | (fa & fb);
                    uint32_t sK = P & (dup * 0x40201u);
                    K[d1] |= sK; K[d2] |= sK;
                }
            #pragma unroll
            for (int d = 0; d < 9; ++d) {
                uint32_t kc = colfold(K[d]);
                uint32_t cols = kc | rotA(kc) | rotB(kc);
                uint32_t em = cols * 0x40201u;
                bd[d] = (bd[d] & ~em) | K[d];
            }
        }

        // ---------- doubles 'box' (band-local) ----------
        {
            uint32_t on = 0, tw = 0, fo = 0;
            #pragma unroll
            for (int d = 0; d < 9; ++d) {
                uint32_t c = on & bd[d];
                on ^= bd[d]; fo |= tw & c; tw ^= c;
            }
            uint32_t ex2 = tw & ~on & ~fo;
            uint32_t Q[9], K[9];
            #pragma unroll
            for (int d = 0; d < 9; ++d) { Q[d] = bd[d] & ex2; K[d] = 0u; }
            #pragma unroll
            for (int d1 = 0; d1 < 9; ++d1)
                #pragma unroll
                for (int d2 = d1 + 1; d2 < 9; ++d2) {
                    uint32_t P = Q[d1] & Q[d2];
                    #pragma unroll
                    for (int k = 0; k < 3; ++k) {
                        uint32_t m = P & (0x1C0E07u << (3 * k));
                        uint32_t s = (m & (m - 1u)) ? m : 0u;
                        K[d1] |= s; K[d2] |= s;
                    }
                }
            #pragma unroll
            for (int d = 0; d < 9; ++d)
                #pragma unroll
                for (int k = 0; k < 3; ++k) {
                    uint32_t bm = 0x1C0E07u << (3 * k);
                    uint32_t t = K[d] & bm;
                    uint32_t mask = t ? (~bm | t) : 0xFFFFFFFFu;
                    bd[d] &= mask;
                }
        }

        // ---------- fixpoint check (wave-uniform break; band-3 excluded) ----------
        {
            uint32_t chg = (bd[0] ^ old0) | (bd[1] ^ old1) | (bd[2] ^ old2)
                         | (bd[3] ^ old3) | (bd[4] ^ old4) | (bd[5] ^ old5)
                         | (bd[6] ^ old6) | (bd[7] ^ old7) | (bd[8] ^ old8);
            if (band == 3) chg = 0;                 // idle lanes hold garbage
            if (__ballot(chg != 0) == 0ull) break;  // whole wave at fixpoint
        }
    } // passes

    // ---------------- solved flag (AND across quad via DPP) ----------------
    {
        uint32_t on = 0, tw = 0, fo = 0;
        #pragma unroll
        for (int d = 0; d < 9; ++d) {
            uint32_t c = on & bd[d];
            on ^= bd[d]; fo |= tw & c; tw ^= c;
        }
        uint32_t okb = ((on & ~tw & ~fo) == FULL27) ? 1u : 0u;
        uint32_t all = okb & rotA(okb) & rotB(okb);
        if (band == 0) solved[P0 + q] = all ? 1.0f : 0.0f;
    }

    // ---------------- EXPAND: repack to pool bitstream -> float4 stores --------
    for (int j = tid; j < BLK_DW + 2; j += 256) pool[j] = 0u;
    __syncthreads();
    if (band != 3) {
        const int pbit = q * 729;
        #pragma unroll
        for (int d = 0; d < 9; ++d) {
            int bitbase = pbit + d * 81 + band * 27;
            int di = bitbase >> 5;
            int sh = bitbase & 31;
            uint64_t both = (uint64_t)bd[d] << sh;
            atomicOr(&pool[di], (uint32_t)both);
            atomicOr(&pool[di + 1], (uint32_t)(both >> 32));
        }
    }
    __syncthreads();
    {
        float4* dst4 = (float4*)(out + (size_t)P0 * 729);  // 46656*blk floats: aligned
        #pragma unroll 4
        for (int i = 0; i < 46; ++i) {                     // 11664 float4s / 256 lanes
            int j = i * 256 + tid;
            if (j < 11664) {
                uint32_t nib = (pool[j >> 3] >> ((j & 7) * 4)) & 0xFu;
                dst4[j] = make_float4((float)(nib & 1u), (float)((nib >> 1) & 1u),
                                      (float)((nib >> 2) & 1u), (float)((nib >> 3) & 1u));
            }
        }
    }
}

extern "C" void kernel_launch(void* const* d_in, const int* in_sizes, int n_in,
                              void* d_out, int out_size, void* d_ws, size_t ws_size,
                              hipStream_t stream) {
    const uint32_t* in = (const uint32_t*)d_in[0];   // float32 bits; 0.0f / 1.0f
    float* out = (float*)d_out;
    float* solved = out + (size_t)NB * 729;
    // single kernel: 512 blocks x 256 threads (2 blocks/CU, 8 waves/CU)
    sudoku_kernel<<<SOLVE_BLKS, 256, 0, stream>>>(in, out, solved);
}

// Round 13
// 213.405 us; speedup vs baseline: 1.0471x; 1.0355x over previous
//
#include <hip/hip_runtime.h>
#include <stdint.h>

#define NB 32768
#define NPASS 4
#define FULL27 0x07FFFFFFu
#define NBF (NB * 729)            // 23,887,872 floats
#define NV4 (NBF / 4)             // 5,971,968 uint4 loads (exact)
#define PACK_BLKS (NV4 / 256)     // 23,328 blocks (exact)
#define PUZ_PER_BLK 64            // solve: 64 puzzles/block (16/wave, 4 lanes each)
#define SOLVE_BLKS (NB / PUZ_PER_BLK)   // 512 blocks x 256 threads = 2048 waves
#define BLK_DW 1458               // 64*729/32 dwords of packed bits per block (exact)

// Per-band bitboard: digit d, band b (rows 3b..3b+2), bit (r*9+c).
// BOX k mask within band: 0x1C0E07 << 3k ; COL c: 0x40201 << c ; ROW r: 0x1FF << 9r
// Flat float layout: puzzle p, digit d, band b, cell j == p*729 + d*81 + b*27 + j.
// Packed ws: continuous bitstream, bit j == float j (u16 t covers floats 16t..16t+15).
//
// SESSION LEDGER:
//   r15 (216.5us): 3 lanes/puzzle, ds_bpermute. kernel 107us.
//   r16 (213.5us): quad DPP bands. LDS_CONF 3.0M->192K, VALUBusy 42->55.
//   r17 (241.6 REGR): solve at 512 waves -> half the SIMDs empty.
//   r18/r20 (216.2): split kernels. SOLVE VERIFIED 71.3-72.6us @ VALUBusy
//     73-75%. Pack was private-chunk loads -> 8x line inflation -> ~34us.
//   r21 (215.6): fused coalesced DPP pack, 512x256. kernel 104.2; pack 31us:
//     grid caps 8 waves/CU -> 1 outstanding 1KB load/wave -> LATENCY-bound.
//   r22 (209.7, BEST): +launch_bounds(256,2). kernel 101.6. Same pack wall.
//   r23 (207.2): sched_barrier pins -> profiled 142 (defeats scheduler).
//   r24 (213.4): global_load_lds ring -> no gain. Compiler/HW won't give the
//     fused shape more outstanding loads, period.
//   r25/r26 (223.5 REGR): or/shift "strength reduction" (x*0x40201 was already
//     v_mul_u32_u24 full-rate) + single-wave stagger (no effect).
//   r27 (221.0): fixpoint early-exit never fires on random data; overhead.
//   r28 (this): split with BOTH shapes right. Pack = 23328x256 coalesced
//     uint4 + DPP-tree -> u16 ws stores (32 waves/CU, BW-bound ~16us).
//     Solve+expand = r20 kernel VERBATIM (71-73us proven). Predict bench ~201.

__device__ __forceinline__ uint32_t colfold(uint32_t w) {
    return (w | (w >> 9) | (w >> 18)) & 0x1FFu;
}
__device__ __forceinline__ uint32_t colmaj2(uint32_t w) {   // columns with >=2 bits in band
    return ((w & (w >> 9)) | ((w | (w >> 9)) & (w >> 18))) & 0x1FFu;
}
// quad_perm rotations within the 4-lane quad: band b reads band (b+1)%3 / (b-1)%3.
// ctrl = sel0 | sel1<<2 | sel2<<4 | sel3<<6 : [1,2,0,0]=0x09 ; [2,0,1,0]=0x12
__device__ __forceinline__ uint32_t rotA(uint32_t v) {      // from band+1 (mod 3)
    return (uint32_t)__builtin_amdgcn_update_dpp(0, (int)v, 0x09, 0xF, 0xF, true);
}
__device__ __forceinline__ uint32_t rotB(uint32_t v) {      // from band-1 (mod 3)
    return (uint32_t)__builtin_amdgcn_update_dpp(0, (int)v, 0x12, 0xF, 0xF, true);
}
// pack-tree swaps: quad_perm [1,0,3,2]=0xB1 (lane^1), [2,3,0,1]=0x4E (lane^2)
__device__ __forceinline__ uint32_t dppx1(uint32_t v) {
    return (uint32_t)__builtin_amdgcn_update_dpp(0, (int)v, 0xB1, 0xF, 0xF, true);
}
__device__ __forceinline__ uint32_t dppx2(uint32_t v) {
    return (uint32_t)__builtin_amdgcn_update_dpp(0, (int)v, 0x4E, 0xF, 0xF, true);
}

// ---------------------------------------------------------------------------
// PACK: thread g loads uint4 #g (coalesced), nibble from exp bit 23, DPP tree
// combines 4 lanes -> u16, lane%4==0 stores ws half-word. 32 waves/CU -> BW.
// ---------------------------------------------------------------------------
__global__ __launch_bounds__(256)
void pack_kernel(const uint32_t* __restrict__ in, uint32_t* __restrict__ ws) {
    const int g = blockIdx.x * 256 + threadIdx.x;      // < NV4 (grid exact)
    const uint4 v = ((const uint4*)in)[g];
    // inputs are exactly 0.0f/1.0f -> bit 23 of the pattern is the flag
    uint32_t n = ((v.x >> 23) & 1u) | ((v.y >> 22) & 2u)
               | ((v.z >> 21) & 4u) | ((v.w >> 20) & 8u);
    uint32_t b = n | (dppx1(n) << 4);                  // byte, valid on even lanes
    uint32_t h = b | (dppx2(b) << 8);                  // u16, valid on lane%4==0
    if ((threadIdx.x & 3) == 0) ((uint16_t*)ws)[g >> 2] = (uint16_t)h;
}

// ---------------------------------------------------------------------------
// SOLVE + EXPAND (r20 VERBATIM, measured 71.3-72.6us): 4 lanes/puzzle,
// 64 puzzles/block, packed bits staged to LDS (1458 dw exact, uint2-aligned).
// ---------------------------------------------------------------------------
__global__ __launch_bounds__(256)
void solve_kernel(const uint32_t* __restrict__ ws, float* __restrict__ out,
                  float* __restrict__ solved) {
    __shared__ uint32_t lds[BLK_DW + 2];    // +2: band-3 lanes read 1 dw past range
    const int tid = threadIdx.x;
    const int q = tid >> 2;                 // puzzle slot 0..63
    const int band = tid & 3;               // 0..2 live, 3 idle in solve
    const int P0 = blockIdx.x * PUZ_PER_BLK;

    // ---- stage packed bits: 729 uint2 loads (block base = 5832B*blk: aligned)
    {
        const uint2* wsrc = (const uint2*)(ws + (size_t)blockIdx.x * BLK_DW);
        uint2* ldst = (uint2*)lds;
        #pragma unroll
        for (int i = 0; i < 3; ++i) {
            int j = i * 256 + tid;
            if (j < 729) ldst[j] = wsrc[j];
        }
    }
    __syncthreads();

    // ---- extract 9 band-words for this lane (band 3 reads in-bounds garbage)
    uint32_t bd[9];
    {
        const int bb0 = q * 729 + band * 27;
        #pragma unroll
        for (int d = 0; d < 9; ++d) {
            int bit = bb0 + d * 81;
            int di = bit >> 5, sh = bit & 31;
            uint64_t both = (uint64_t)lds[di] | ((uint64_t)lds[di + 1] << 32);
            bd[d] = (uint32_t)(both >> sh) & FULL27;
        }
    }
    __syncthreads();    // extraction done before pool reuse for expand

    // ---------------- SOLVE (r16/r20-validated quad-DPP logic, unchanged) ------
    #pragma unroll 1
    for (int pass = 0; pass < NPASS; ++pass) {
        // ---------- filter 'box' (band-local) ----------
        {
            uint32_t on = 0, tw = 0, fo = 0;
            #pragma unroll
            for (int d = 0; d < 9; ++d) {
                uint32_t c = on & bd[d];
                on ^= bd[d]; fo |= tw & c; tw ^= c;
            }
            uint32_t ex1 = on & ~tw & ~fo;
            #pragma unroll
            for (int d = 0; d < 9; ++d) {
                uint32_t s = bd[d] & ex1;
                #pragma unroll
                for (int k = 0; k < 3; ++k) {
                    uint32_t bm = 0x1C0E07u << (3 * k);
                    uint32_t sm = s & bm;
                    uint32_t multi = sm & (sm - 1u);
                    uint32_t keep = (sm == 0u) ? 0xFFFFFFFFu : (~bm | (multi ? 0u : sm));
                    bd[d] &= keep;
                }
            }
        }

        // ---------- pointing 'h' (band-local) ----------
        #pragma unroll
        for (int d = 0; d < 9; ++d) {
            uint32_t w = bd[d];
            uint32_t t = (w | (w >> 1) | (w >> 2)) & 0x01249249u;
            uint32_t sum = (t & 0x1FFu) + ((t >> 9) & 0x1FFu) + ((t >> 18) & 0x1FFu);
            uint32_t single = sum & ~(sum >> 1) & 0x49u;
            uint32_t point = t & (single * 0x40201u);
            uint32_t clearm = 0;
            #pragma unroll
            for (int r = 0; r < 3; ++r) {
                uint32_t pr = (point >> (9 * r)) & 0x1FFu;
                uint32_t multi = pr & (pr - 1u);
                uint32_t segkeep = multi ? 0u : pr * 7u;
                uint32_t rc = pr ? ((0x1FFu & ~segkeep) << (9 * r)) : 0u;
                clearm |= rc;
            }
            bd[d] = w & ~clearm;
        }

        // ---------- pointing 'v' (cross-band via DPP) ----------
        {
            uint32_t pnt[9];
            #pragma unroll
            for (int d = 0; d < 9; ++d) {
                uint32_t w = bd[d];
                uint32_t qq = colfold(w);
                uint32_t u = (qq & 0x49u) + ((qq >> 1) & 0x49u) + ((qq >> 2) & 0x49u);
                uint32_t single = u & ~(u >> 1) & 0x49u;
                pnt[d] = qq & (single * 7u);
            }
            #pragma unroll
            for (int d = 0; d < 9; ++d) {
                uint32_t o = rotA(pnt[d]) | rotB(pnt[d]);
                bd[d] &= ~(o * 0x40201u);
            }
        }

        // ---------- unique 'h' (band-local) ----------
        {
            uint32_t hid[9], has = 0;
            #pragma unroll
            for (int d = 0; d < 9; ++d) {
                uint32_t w = bd[d], h = 0;
                #pragma unroll
                for (int r = 0; r < 3; ++r) {
                    uint32_t x = w & (0x1FFu << (9 * r));
                    h |= (x & (x - 1u)) ? 0u : x;
                }
                hid[d] = h; has |= h;
            }
            #pragma unroll
            for (int d = 0; d < 9; ++d) bd[d] = (bd[d] & ~has) | hid[d];
        }

        // ---------- unique 'v' (cross-band via DPP) ----------
        {
            uint32_t hid[9], has = 0;
            #pragma unroll
            for (int d = 0; d < 9; ++d) {
                uint32_t w = bd[d];
                uint32_t q0 = colfold(w), m0 = colmaj2(w);
                uint32_t ex = q0 | (m0 << 9);
                uint32_t ea = rotA(ex);
                uint32_t eb = rotB(ex);
                uint32_t qa = ea & 0x1FFu, ma = ea >> 9;
                uint32_t qb = eb & 0x1FFu, mb = eb >> 9;
                uint32_t ge2 = m0 | ma | mb | (q0 & qa) | (q0 & qb) | (qa & qb);
                uint32_t ex1c = (q0 | qa | qb) & ~ge2;   // column total count == 1
                hid[d] = w & ((ex1c & q0) * 0x40201u);
                has |= hid[d];
            }
            #pragma unroll
            for (int d = 0; d < 9; ++d) bd[d] = (bd[d] & ~has) | hid[d];
        }

        // ---------- unique 'box' (band-local) ----------
        {
            uint32_t hid[9], has = 0;
            #pragma unroll
            for (int d = 0; d < 9; ++d) {
                uint32_t w = bd[d], h = 0;
                #pragma unroll
                for (int k = 0; k < 3; ++k) {
                    uint32_t x = w & (0x1C0E07u << (3 * k));
                    h |= (x & (x - 1u)) ? 0u : x;
                }
                hid[d] = h; has |= h;
            }
            #pragma unroll
            for (int d = 0; d < 9; ++d) bd[d] = (bd[d] & ~has) | hid[d];
        }

        // ---------- doubles 'v' twice (cross-band via DPP) ----------
        #pragma unroll 1
        for (int rep = 0; rep < 2; ++rep) {
            uint32_t on = 0, tw = 0, fo = 0;
            #pragma unroll
            for (int d = 0; d < 9; ++d) {
                uint32_t c = on & bd[d];
                on ^= bd[d]; fo |= tw & c; tw ^= c;
            }
            uint32_t ex2 = tw & ~on & ~fo;
            uint32_t Q[9], K[9];
            #pragma unroll
            for (int d = 0; d < 9; ++d) { Q[d] = bd[d] & ex2; K[d] = 0u; }
            #pragma unroll
            for (int d1 = 0; d1 < 9; ++d1)
                #pragma unroll
                for (int d2 = d1 + 1; d2 < 9; ++d2) {
                    uint32_t P = Q[d1] & Q[d2];
                    uint32_t f0 = colfold(P), g0 = colmaj2(P);
                    uint32_t ex = f0 | (g0 << 9);
                    uint32_t ea = rotA(ex);
                    uint32_t eb = rotB(ex);
                    uint32_t fa = ea & 0x1FFu, ga = ea >> 9;
                    uint32_t fb = eb & 0x1FFu, gb = eb >> 9;
                    // columns with >=2 exact-pair cells across the full column
                    uint32_t dup = g0 | ga | gb | (f0 & fa) | (f0 & fb) | (fa & fb);
                    uint32_t sK = P & (dup * 0x40201u);
                    K[d1] |= sK; K[d2] |= sK;
                }
            #pragma unroll
            for (int d = 0; d < 9; ++d) {
                uint32_t kc = colfold(K[d]);
                uint32_t cols = kc | rotA(kc) | rotB(kc);
                uint32_t em = cols * 0x40201u;
                bd[d] = (bd[d] & ~em) | K[d];
            }
        }

        // ---------- doubles 'box' (band-local) ----------
        {
            uint32_t on = 0, tw = 0, fo = 0;
            #pragma unroll
            for (int d = 0; d < 9; ++d) {
                uint32_t c = on & bd[d];
                on ^= bd[d]; fo |= tw & c; tw ^= c;
            }
            uint32_t ex2 = tw & ~on & ~fo;
            uint32_t Q[9], K[9];
            #pragma unroll
            for (int d = 0; d < 9; ++d) { Q[d] = bd[d] & ex2; K[d] = 0u; }
            #pragma unroll
            for (int d1 = 0; d1 < 9; ++d1)
                #pragma unroll
                for (int d2 = d1 + 1; d2 < 9; ++d2) {
                    uint32_t P = Q[d1] & Q[d2];
                    #pragma unroll
                    for (int k = 0; k < 3; ++k) {
                        uint32_t m = P & (0x1C0E07u << (3 * k));
                        uint32_t s = (m & (m - 1u)) ? m : 0u;
                        K[d1] |= s; K[d2] |= s;
                    }
                }
            #pragma unroll
            for (int d = 0; d < 9; ++d)
                #pragma unroll
                for (int k = 0; k < 3; ++k) {
                    uint32_t bm = 0x1C0E07u << (3 * k);
                    uint32_t t = K[d] & bm;
                    uint32_t mask = t ? (~bm | t) : 0xFFFFFFFFu;
                    bd[d] &= mask;
                }
        }
    } // passes

    // ---------------- solved flag (AND across quad via DPP) ----------------
    {
        uint32_t on = 0, tw = 0, fo = 0;
        #pragma unroll
        for (int d = 0; d < 9; ++d) {
            uint32_t c = on & bd[d];
            on ^= bd[d]; fo |= tw & c; tw ^= c;
        }
        uint32_t okb = ((on & ~tw & ~fo) == FULL27) ? 1u : 0u;
        uint32_t all = okb & rotA(okb) & rotB(okb);
        if (band == 0) solved[P0 + q] = all ? 1.0f : 0.0f;
    }

    // ---------------- EXPAND: repack to LDS bitstream -> float4 stores ---------
    for (int j = tid; j < BLK_DW + 2; j += 256) lds[j] = 0u;
    __syncthreads();
    if (band != 3) {
        const int pbit = q * 729;
        #pragma unroll
        for (int d = 0; d < 9; ++d) {
            int bitbase = pbit + d * 81 + band * 27;
            int di = bitbase >> 5;
            int sh = bitbase & 31;
            uint64_t both = (uint64_t)bd[d] << sh;
            atomicOr(&lds[di], (uint32_t)both);
            atomicOr(&lds[di + 1], (uint32_t)(both >> 32));
        }
    }
    __syncthreads();
    {
        float4* dst4 = (float4*)(out + (size_t)P0 * 729);  // 46656*blk floats: aligned
        #pragma unroll 4
        for (int i = 0; i < 46; ++i) {                     // 11664 float4s / 256 lanes
            int j = i * 256 + tid;
            if (j < 11664) {
                uint32_t nib = (lds[j >> 3] >> ((j & 7) * 4)) & 0xFu;
                dst4[j] = make_float4((float)(nib & 1u), (float)((nib >> 1) & 1u),
                                      (float)((nib >> 2) & 1u), (float)((nib >> 3) & 1u));
            }
        }
    }
}

extern "C" void kernel_launch(void* const* d_in, const int* in_sizes, int n_in,
                              void* d_out, int out_size, void* d_ws, size_t ws_size,
                              hipStream_t stream) {
    const uint32_t* in = (const uint32_t*)d_in[0];   // float32 bits; 0.0f / 1.0f
    float* out = (float*)d_out;
    float* solved = out + (size_t)NB * 729;
    uint32_t* ws = (uint32_t*)d_ws;                  // 746,496 dwords = 2.98 MB

    pack_kernel<<<PACK_BLKS, 256, 0, stream>>>(in, ws);
    solve_kernel<<<SOLVE_BLKS, 256, 0, stream>>>(ws, out, solved);
}